// Round 3
// baseline (1707.428 us; speedup 1.0000x reference)
//
#include <hip/hip_runtime.h>
#include <math.h>

#define ROUTIT 6

// ---------------------------------------------------------------------------
// Index dtype detection: harness doc says integer inputs arrive as int32,
// but the reference declares int64. Detect at runtime: if indices are int64
// (values < 2^31), every odd 32-bit word of the buffer is 0. Probability of
// that for 32 random int32 indices is ~0. One thread, one flag.
// ---------------------------------------------------------------------------
__global__ void detect_idx64_kernel(const int* __restrict__ raw, int* __restrict__ flag)
{
    int all_zero = 1;
    for (int i = 1; i < 64; i += 2)
        if (raw[i] != 0) { all_zero = 0; break; }
    *flag = all_zero;   // 1 => int64 encoding, 0 => int32
}

__device__ __forceinline__ int load_idx(const void* p, long long i, int is64)
{
    if (is64) return (int)((const long long*)p)[i];
    return ((const int*)p)[i];
}

// ---------------------------------------------------------------------------
// GEMM + per-channel L2 normalize:
//   h[i][j] = sum_l x[i][l]*W[j][l] + b[j];  then l2norm over each 32-chunk.
// One block = 32 rows, 256 threads; each thread computes 4 rows x 4 cols.
// W staged transposed into LDS in 4 l-chunks of 32 (16.9 KB + 16 KB xs).
// ---------------------------------------------------------------------------
__global__ __launch_bounds__(256)
void gemm_norm_kernel(const float* __restrict__ x, const float* __restrict__ W,
                      const float* __restrict__ b, float* __restrict__ h, int n)
{
    __shared__ float WT[32 * 132];    // WT[lc*132 + j] = W[j][l0+lc]
    __shared__ float xs[32 * 128];

    const int tid  = threadIdx.x;
    const int jc   = tid & 31;        // col group: cols jc*4 .. jc*4+3
    const int rg   = tid >> 5;        // row group: rows rg*4 .. rg*4+3
    const int row0 = blockIdx.x * 32;
    const int ntot = n * 128;

    for (int t = 0; t < 16; ++t) {
        int idx  = t * 256 + tid;
        int gidx = row0 * 128 + idx;
        xs[idx] = (gidx < ntot) ? x[gidx] : 0.0f;
    }

    float4 bb = ((const float4*)b)[jc];
    float acc[4][4];
    #pragma unroll
    for (int ri = 0; ri < 4; ++ri) {
        acc[ri][0] = bb.x; acc[ri][1] = bb.y; acc[ri][2] = bb.z; acc[ri][3] = bb.w;
    }

    for (int l0 = 0; l0 < 128; l0 += 32) {
        __syncthreads();
        for (int t = 0; t < 16; ++t) {
            int idx = t * 256 + tid;
            int j = idx >> 5, lc = idx & 31;
            WT[lc * 132 + j] = W[j * 128 + l0 + lc];
        }
        __syncthreads();

        #pragma unroll 8
        for (int lc = 0; lc < 32; ++lc) {
            float4 wt = ((const float4*)(WT + lc * 132))[jc];
            #pragma unroll
            for (int ri = 0; ri < 4; ++ri) {
                float xv = xs[(rg * 4 + ri) * 128 + l0 + lc];
                acc[ri][0] += xv * wt.x;
                acc[ri][1] += xv * wt.y;
                acc[ri][2] += xv * wt.z;
                acc[ri][3] += xv * wt.w;
            }
        }
    }

    #pragma unroll
    for (int ri = 0; ri < 4; ++ri) {
        float ss = acc[ri][0]*acc[ri][0] + acc[ri][1]*acc[ri][1]
                 + acc[ri][2]*acc[ri][2] + acc[ri][3]*acc[ri][3];
        ss += __shfl_xor(ss, 1);
        ss += __shfl_xor(ss, 2);
        ss += __shfl_xor(ss, 4);
        float inv = 1.0f / fmaxf(sqrtf(ss), 1e-12f);
        int row = row0 + rg * 4 + ri;
        if (row < n) {
            float4 o;
            o.x = acc[ri][0]*inv; o.y = acc[ri][1]*inv;
            o.z = acc[ri][2]*inv; o.w = acc[ri][3]*inv;
            ((float4*)(h + (size_t)row * 128))[jc] = o;
        }
    }
}

// ---------------------------------------------------------------------------
// CSR build: per-target edge lists
// ---------------------------------------------------------------------------
__global__ void zero_kernel(int* __restrict__ p, int n)
{
    int i = blockIdx.x * blockDim.x + threadIdx.x;
    if (i < n) p[i] = 0;
}

__global__ void hist_kernel(const void* __restrict__ st, long long m, int n,
                            const int* __restrict__ idx64, int* __restrict__ cnt)
{
    long long e = (long long)blockIdx.x * blockDim.x + threadIdx.x;
    if (e < m) {
        int t = load_idx(st, m + e, *idx64);   // trg = row 1 of (2,m)
        if (t >= 0 && t < n) atomicAdd(&cnt[t], 1);
    }
}

__global__ __launch_bounds__(1024)
void scan_kernel(const int* __restrict__ cnt, int n,
                 int* __restrict__ row_ptr, int* __restrict__ cursor)
{
    __shared__ int lds[1024];
    int t = threadIdx.x;
    int per = (n + 1023) / 1024;
    int lo = min(t * per, n), hi = min(lo + per, n);
    int s = 0;
    for (int i = lo; i < hi; ++i) s += cnt[i];
    lds[t] = s;
    __syncthreads();
    for (int off = 1; off < 1024; off <<= 1) {
        int v = (t >= off) ? lds[t - off] : 0;
        __syncthreads();
        lds[t] += v;
        __syncthreads();
    }
    int run = lds[t] - s;                  // exclusive prefix of this chunk
    for (int i = lo; i < hi; ++i) {
        row_ptr[i] = run; cursor[i] = run; run += cnt[i];
    }
    if (t == 0) row_ptr[n] = lds[1023];
}

__global__ void scatter_kernel(const void* __restrict__ st, long long m, int n,
                               const int* __restrict__ idx64,
                               int* __restrict__ cursor, int* __restrict__ edge_src)
{
    long long e = (long long)blockIdx.x * blockDim.x + threadIdx.x;
    if (e < m) {
        int is64 = *idx64;
        int t = load_idx(st, m + e, is64);
        int s = load_idx(st, e, is64);
        if (t >= 0 && t < n) {
            int pos = atomicAdd(&cursor[t], 1);
            edge_src[pos] = s;
        }
    }
}

// ---------------------------------------------------------------------------
// Routing: one wave per node, all 6 iterations fused, c row in registers
// (2 floats/lane; channel = lane>>4).
// c_new[t] = l2norm(c_old[t] + sum_e softmax_k(h[src_e] . c_old[t]) * h[src_e])
// z = h[src] is fixed and the scatter reads pre-update c, so there is no
// cross-node dependency within an iteration: no atomics, no ping-pong.
// ---------------------------------------------------------------------------
__global__ __launch_bounds__(256)
void route_kernel(const float* __restrict__ h, const int* __restrict__ row_ptr,
                  const int* __restrict__ edge_src, float* __restrict__ out, int n)
{
    int wid  = (blockIdx.x * 256 + threadIdx.x) >> 6;
    int lane = threadIdx.x & 63;
    if (wid >= n) return;

    const float2* __restrict__ h2 = (const float2*)h;
    float2 c = h2[(size_t)wid * 64 + lane];
    int e0 = row_ptr[wid], e1 = row_ptr[wid + 1];

    for (int it = 0; it < ROUTIT; ++it) {
        float a0 = c.x, a1 = c.y;
        for (int e = e0; e < e1; ++e) {
            int s = edge_src[e];
            float2 z = h2[(size_t)s * 64 + lane];
            float p = z.x * c.x + z.y * c.y;
            p += __shfl_xor(p, 1);
            p += __shfl_xor(p, 2);
            p += __shfl_xor(p, 4);
            p += __shfl_xor(p, 8);
            int base = lane & 15;
            float d0 = __shfl(p, base);
            float d1 = __shfl(p, base + 16);
            float d2 = __shfl(p, base + 32);
            float d3 = __shfl(p, base + 48);
            float mx = fmaxf(fmaxf(d0, d1), fmaxf(d2, d3));
            float s0 = __expf(d0 - mx), s1 = __expf(d1 - mx);
            float s2 = __expf(d2 - mx), s3 = __expf(d3 - mx);
            float w  = __expf(p - mx) / (s0 + s1 + s2 + s3);
            a0 += w * z.x;
            a1 += w * z.y;
        }
        float ss = a0 * a0 + a1 * a1;
        ss += __shfl_xor(ss, 1);
        ss += __shfl_xor(ss, 2);
        ss += __shfl_xor(ss, 4);
        ss += __shfl_xor(ss, 8);
        float inv = 1.0f / fmaxf(sqrtf(ss), 1e-12f);
        c.x = a0 * inv;
        c.y = a1 * inv;
    }
    ((float2*)out)[(size_t)wid * 64 + lane] = c;
}

// ---------------------------------------------------------------------------
extern "C" void kernel_launch(void* const* d_in, const int* in_sizes, int n_in,
                              void* d_out, int out_size, void* d_ws, size_t ws_size,
                              hipStream_t stream)
{
    const float* x       = (const float*)d_in[0];
    const void*  src_trg = d_in[1];
    const float* W       = (const float*)d_in[2];
    const float* b       = (const float*)d_in[3];
    float*       out     = (float*)d_out;

    int n = in_sizes[0] / 128;
    long long m = in_sizes[1] / 2;

    // workspace layout (~58.9 MB)
    float* h        = (float*)d_ws;                    // n*128 floats (51.2 MB)
    int*   cnt      = (int*)(h + (size_t)n * 128);     // n
    int*   row_ptr  = cnt + n;                         // n+1
    int*   cursor   = row_ptr + (n + 1);               // n
    int*   edge_src = cursor + n;                      // m ints (6.4 MB)
    int*   idx64    = edge_src + m;                    // 1 flag

    hipLaunchKernelGGL(detect_idx64_kernel, dim3(1), dim3(1), 0, stream,
                       (const int*)src_trg, idx64);
    hipLaunchKernelGGL(gemm_norm_kernel, dim3((n + 31) / 32), dim3(256), 0, stream,
                       x, W, b, h, n);
    hipLaunchKernelGGL(zero_kernel, dim3((n + 255) / 256), dim3(256), 0, stream, cnt, n);
    hipLaunchKernelGGL(hist_kernel, dim3((int)((m + 255) / 256)), dim3(256), 0, stream,
                       src_trg, m, n, idx64, cnt);
    hipLaunchKernelGGL(scan_kernel, dim3(1), dim3(1024), 0, stream, cnt, n, row_ptr, cursor);
    hipLaunchKernelGGL(scatter_kernel, dim3((int)((m + 255) / 256)), dim3(256), 0, stream,
                       src_trg, m, n, idx64, cursor, edge_src);
    hipLaunchKernelGGL(route_kernel, dim3((n + 3) / 4), dim3(256), 0, stream,
                       h, row_ptr, edge_src, out, n);
}

// Round 4
// 1128.517 us; speedup vs baseline: 1.5130x; 1.5130x over previous
//
#include <hip/hip_runtime.h>
#include <math.h>

#define ROUTIT 6

// ---------------------------------------------------------------------------
// Index dtype detection: harness doc says integer inputs arrive as int32,
// but the reference declares int64. Detect at runtime: if indices are int64
// (values < 2^31), every odd 32-bit word of the buffer is 0. Probability of
// that for 32 random int32 indices in [0,100000) is ~0. One thread, one flag.
// ---------------------------------------------------------------------------
__global__ void detect_idx64_kernel(const int* __restrict__ raw, int* __restrict__ flag)
{
    int all_zero = 1;
    for (int i = 1; i < 64; i += 2)
        if (raw[i] != 0) { all_zero = 0; break; }
    *flag = all_zero;   // 1 => int64 encoding, 0 => int32
}

__device__ __forceinline__ int load_idx(const void* p, long long i, int is64)
{
    if (is64) return (int)((const long long*)p)[i];
    return ((const int*)p)[i];
}

// ---------------------------------------------------------------------------
// GEMM + per-channel L2 normalize:
//   h[i][j] = sum_l x[i][l]*W[j][l] + b[j];  then l2norm over each 32-chunk.
// One block = 32 rows, 256 threads; each thread computes 4 rows x 4 cols.
// W staged transposed into LDS in 4 l-chunks of 32 (16.9 KB + 16 KB xs).
// ---------------------------------------------------------------------------
__global__ __launch_bounds__(256)
void gemm_norm_kernel(const float* __restrict__ x, const float* __restrict__ W,
                      const float* __restrict__ b, float* __restrict__ h, int n)
{
    __shared__ float WT[32 * 132];    // WT[lc*132 + j] = W[j][l0+lc]
    __shared__ float xs[32 * 128];

    const int tid  = threadIdx.x;
    const int jc   = tid & 31;        // col group: cols jc*4 .. jc*4+3
    const int rg   = tid >> 5;        // row group: rows rg*4 .. rg*4+3
    const int row0 = blockIdx.x * 32;
    const int ntot = n * 128;

    for (int t = 0; t < 16; ++t) {
        int idx  = t * 256 + tid;
        int gidx = row0 * 128 + idx;
        xs[idx] = (gidx < ntot) ? x[gidx] : 0.0f;
    }

    float4 bb = ((const float4*)b)[jc];
    float acc[4][4];
    #pragma unroll
    for (int ri = 0; ri < 4; ++ri) {
        acc[ri][0] = bb.x; acc[ri][1] = bb.y; acc[ri][2] = bb.z; acc[ri][3] = bb.w;
    }

    for (int l0 = 0; l0 < 128; l0 += 32) {
        __syncthreads();
        for (int t = 0; t < 16; ++t) {
            int idx = t * 256 + tid;
            int j = idx >> 5, lc = idx & 31;
            WT[lc * 132 + j] = W[j * 128 + l0 + lc];
        }
        __syncthreads();

        #pragma unroll 8
        for (int lc = 0; lc < 32; ++lc) {
            float4 wt = ((const float4*)(WT + lc * 132))[jc];
            #pragma unroll
            for (int ri = 0; ri < 4; ++ri) {
                float xv = xs[(rg * 4 + ri) * 128 + l0 + lc];
                acc[ri][0] += xv * wt.x;
                acc[ri][1] += xv * wt.y;
                acc[ri][2] += xv * wt.z;
                acc[ri][3] += xv * wt.w;
            }
        }
    }

    #pragma unroll
    for (int ri = 0; ri < 4; ++ri) {
        float ss = acc[ri][0]*acc[ri][0] + acc[ri][1]*acc[ri][1]
                 + acc[ri][2]*acc[ri][2] + acc[ri][3]*acc[ri][3];
        ss += __shfl_xor(ss, 1);
        ss += __shfl_xor(ss, 2);
        ss += __shfl_xor(ss, 4);
        float inv = 1.0f / fmaxf(sqrtf(ss), 1e-12f);
        int row = row0 + rg * 4 + ri;
        if (row < n) {
            float4 o;
            o.x = acc[ri][0]*inv; o.y = acc[ri][1]*inv;
            o.z = acc[ri][2]*inv; o.w = acc[ri][3]*inv;
            ((float4*)(h + (size_t)row * 128))[jc] = o;
        }
    }
}

// ---------------------------------------------------------------------------
// CSR build: per-target edge lists
// ---------------------------------------------------------------------------
__global__ void zero_kernel(int* __restrict__ p, int n)
{
    int i = blockIdx.x * blockDim.x + threadIdx.x;
    if (i < n) p[i] = 0;
}

__global__ void hist_kernel(const void* __restrict__ st, long long m, int n,
                            const int* __restrict__ idx64, int* __restrict__ cnt)
{
    long long e = (long long)blockIdx.x * blockDim.x + threadIdx.x;
    if (e < m) {
        int t = load_idx(st, m + e, *idx64);   // trg = row 1 of (2,m)
        if (t >= 0 && t < n) atomicAdd(&cnt[t], 1);
    }
}

__global__ __launch_bounds__(1024)
void scan_kernel(const int* __restrict__ cnt, int n,
                 int* __restrict__ row_ptr, int* __restrict__ cursor)
{
    __shared__ int lds[1024];
    int t = threadIdx.x;
    int per = (n + 1023) / 1024;
    int lo = min(t * per, n), hi = min(lo + per, n);
    int s = 0;
    for (int i = lo; i < hi; ++i) s += cnt[i];
    lds[t] = s;
    __syncthreads();
    for (int off = 1; off < 1024; off <<= 1) {
        int v = (t >= off) ? lds[t - off] : 0;
        __syncthreads();
        lds[t] += v;
        __syncthreads();
    }
    int run = lds[t] - s;                  // exclusive prefix of this chunk
    for (int i = lo; i < hi; ++i) {
        row_ptr[i] = run; cursor[i] = run; run += cnt[i];
    }
    if (t == 0) row_ptr[n] = lds[1023];
}

__global__ void scatter_kernel(const void* __restrict__ st, long long m, int n,
                               const int* __restrict__ idx64,
                               int* __restrict__ cursor, int* __restrict__ edge_src)
{
    long long e = (long long)blockIdx.x * blockDim.x + threadIdx.x;
    if (e < m) {
        int is64 = *idx64;
        int t = load_idx(st, m + e, is64);
        int s = load_idx(st, e, is64);
        if (t >= 0 && t < n) {
            int pos = atomicAdd(&cursor[t], 1);
            edge_src[pos] = s;
        }
    }
}

// ---------------------------------------------------------------------------
// Routing: one wave per node, all 6 iterations fused, c row in registers
// (2 floats/lane; channel = lane>>4).
// c_new[t] = l2norm(c_old[t] + sum_e softmax_k(h[src_e] . c_old[t]) * h[src_e])
//
// VALU diet vs previous round:
//  - |dot| <= 1 (unit-norm channels), so softmax needs NO max subtraction:
//    1 exp + 2 cross-channel shfl_xor instead of 5 exps + 4 bpermute + fmax.
//  - v_rcp instead of precise division (~12 instrs -> 1).
//  - wid through readfirstlane => edge list + loop bounds become scalar
//    (s_load), gather base in SGPR.
//  - 2-way edge unroll: two independent shuffle/exp chains interleave.
// ---------------------------------------------------------------------------
__global__ __launch_bounds__(256)
void route_kernel(const float* __restrict__ h, const int* __restrict__ row_ptr,
                  const int* __restrict__ edge_src, float* __restrict__ out, int n)
{
    int wid  = (int)((blockIdx.x * 256u + threadIdx.x) >> 6);
    wid = __builtin_amdgcn_readfirstlane(wid);   // wave-uniform, make it scalar
    int lane = threadIdx.x & 63;
    if (wid >= n) return;

    const float2* __restrict__ h2 = (const float2*)h;
    float2 c = h2[(size_t)wid * 64 + lane];
    const int e0 = row_ptr[wid], e1 = row_ptr[wid + 1];

    #pragma unroll 1
    for (int it = 0; it < ROUTIT; ++it) {
        float a0 = c.x, a1 = c.y;
        int e = e0;
        for (; e + 1 < e1; e += 2) {
            int sa = edge_src[e];
            int sb = edge_src[e + 1];
            float2 za = h2[(size_t)sa * 64 + lane];
            float2 zb = h2[(size_t)sb * 64 + lane];
            float pa = za.x * c.x + za.y * c.y;
            float pb = zb.x * c.x + zb.y * c.y;
            pa += __shfl_xor(pa, 1);  pb += __shfl_xor(pb, 1);
            pa += __shfl_xor(pa, 2);  pb += __shfl_xor(pb, 2);
            pa += __shfl_xor(pa, 4);  pb += __shfl_xor(pb, 4);
            pa += __shfl_xor(pa, 8);  pb += __shfl_xor(pb, 8);
            float ea = __expf(pa), eb = __expf(pb);     // |p|<=1, no overflow
            float da = ea + __shfl_xor(ea, 16);
            float db = eb + __shfl_xor(eb, 16);
            da += __shfl_xor(da, 32);
            db += __shfl_xor(db, 32);
            float wa = ea * __builtin_amdgcn_rcpf(da);
            float wb = eb * __builtin_amdgcn_rcpf(db);
            a0 += wa * za.x;  a1 += wa * za.y;
            a0 += wb * zb.x;  a1 += wb * zb.y;
        }
        if (e < e1) {
            int s = edge_src[e];
            float2 z = h2[(size_t)s * 64 + lane];
            float p = z.x * c.x + z.y * c.y;
            p += __shfl_xor(p, 1);
            p += __shfl_xor(p, 2);
            p += __shfl_xor(p, 4);
            p += __shfl_xor(p, 8);
            float ex = __expf(p);
            float d = ex + __shfl_xor(ex, 16);
            d += __shfl_xor(d, 32);
            float w = ex * __builtin_amdgcn_rcpf(d);
            a0 += w * z.x;  a1 += w * z.y;
        }
        // per-channel l2norm (32 elems live in the 16-lane channel group)
        float ss = a0 * a0 + a1 * a1;
        ss += __shfl_xor(ss, 1);
        ss += __shfl_xor(ss, 2);
        ss += __shfl_xor(ss, 4);
        ss += __shfl_xor(ss, 8);
        float inv = __builtin_amdgcn_rcpf(fmaxf(sqrtf(ss), 1e-12f));
        c.x = a0 * inv;
        c.y = a1 * inv;
    }
    ((float2*)out)[(size_t)wid * 64 + lane] = c;
}

// ---------------------------------------------------------------------------
extern "C" void kernel_launch(void* const* d_in, const int* in_sizes, int n_in,
                              void* d_out, int out_size, void* d_ws, size_t ws_size,
                              hipStream_t stream)
{
    const float* x       = (const float*)d_in[0];
    const void*  src_trg = d_in[1];
    const float* W       = (const float*)d_in[2];
    const float* b       = (const float*)d_in[3];
    float*       out     = (float*)d_out;

    int n = in_sizes[0] / 128;
    long long m = in_sizes[1] / 2;

    // workspace layout (~58.9 MB)
    float* h        = (float*)d_ws;                    // n*128 floats (51.2 MB)
    int*   cnt      = (int*)(h + (size_t)n * 128);     // n
    int*   row_ptr  = cnt + n;                         // n+1
    int*   cursor   = row_ptr + (n + 1);               // n
    int*   edge_src = cursor + n;                      // m ints (6.4 MB)
    int*   idx64    = edge_src + m;                    // 1 flag

    hipLaunchKernelGGL(detect_idx64_kernel, dim3(1), dim3(1), 0, stream,
                       (const int*)src_trg, idx64);
    hipLaunchKernelGGL(gemm_norm_kernel, dim3((n + 31) / 32), dim3(256), 0, stream,
                       x, W, b, h, n);
    hipLaunchKernelGGL(zero_kernel, dim3((n + 255) / 256), dim3(256), 0, stream, cnt, n);
    hipLaunchKernelGGL(hist_kernel, dim3((int)((m + 255) / 256)), dim3(256), 0, stream,
                       src_trg, m, n, idx64, cnt);
    hipLaunchKernelGGL(scan_kernel, dim3(1), dim3(1024), 0, stream, cnt, n, row_ptr, cursor);
    hipLaunchKernelGGL(scatter_kernel, dim3((int)((m + 255) / 256)), dim3(256), 0, stream,
                       src_trg, m, n, idx64, cursor, edge_src);
    hipLaunchKernelGGL(route_kernel, dim3((n + 3) / 4), dim3(256), 0, stream,
                       h, row_ptr, edge_src, out, n);
}

// Round 8
// 1080.849 us; speedup vs baseline: 1.5797x; 1.0441x over previous
//
#include <hip/hip_runtime.h>
#include <math.h>

#define ROUTIT 6

// ---------------------------------------------------------------------------
// Index dtype detection (harness delivers int indices as int32; reference
// declares int64 — detect which encoding is present at runtime).
// ---------------------------------------------------------------------------
__global__ void detect_idx64_kernel(const int* __restrict__ raw, int* __restrict__ flag)
{
    int all_zero = 1;
    for (int i = 1; i < 64; i += 2)
        if (raw[i] != 0) { all_zero = 0; break; }
    *flag = all_zero;   // 1 => int64 encoding, 0 => int32
}

__device__ __forceinline__ int load_idx(const void* p, long long i, int is64)
{
    if (is64) return (int)((const long long*)p)[i];
    return ((const int*)p)[i];
}

// ---------------------------------------------------------------------------
// Intra-row (16-lane) sum via DPP — the rocPRIM wave-reduce idiom (VALU pipe,
// no DS). Cross-row sums stay on proven __shfl_xor (DS) this round: this
// isolates the round-6/7 accuracy bug to the permlane-swap asm, which is
// removed entirely.
// ---------------------------------------------------------------------------
template <int CTRL>
__device__ __forceinline__ float dpp_add(float x)
{
    int y = __builtin_amdgcn_update_dpp(0, __float_as_int(x), CTRL, 0xf, 0xf, true);
    return x + __int_as_float(y);
}

// sum over the 16-lane row (every lane of the row gets the total)
__device__ __forceinline__ float rowsum16(float p)
{
    p = dpp_add<0xB1>(p);   // quad_perm [1,0,3,2] : xor 1
    p = dpp_add<0x4E>(p);   // quad_perm [2,3,0,1] : xor 2
    p = dpp_add<0x124>(p);  // row_ror:4
    p = dpp_add<0x128>(p);  // row_ror:8
    return p;
}

// ---------------------------------------------------------------------------
// GEMM + per-channel L2 normalize (fp32 h).
// ---------------------------------------------------------------------------
__global__ __launch_bounds__(256)
void gemm_norm_kernel(const float* __restrict__ x, const float* __restrict__ W,
                      const float* __restrict__ b, float* __restrict__ h, int n)
{
    __shared__ float WT[32 * 132];    // WT[lc*132 + j] = W[j][l0+lc]
    __shared__ float xs[32 * 128];

    const int tid  = threadIdx.x;
    const int jc   = tid & 31;        // col group: cols jc*4 .. jc*4+3
    const int rg   = tid >> 5;        // row group: rows rg*4 .. rg*4+3
    const int row0 = blockIdx.x * 32;
    const int ntot = n * 128;

    for (int t = 0; t < 16; ++t) {
        int idx  = t * 256 + tid;
        int gidx = row0 * 128 + idx;
        xs[idx] = (gidx < ntot) ? x[gidx] : 0.0f;
    }

    float4 bb = ((const float4*)b)[jc];
    float acc[4][4];
    #pragma unroll
    for (int ri = 0; ri < 4; ++ri) {
        acc[ri][0] = bb.x; acc[ri][1] = bb.y; acc[ri][2] = bb.z; acc[ri][3] = bb.w;
    }

    for (int l0 = 0; l0 < 128; l0 += 32) {
        __syncthreads();
        for (int t = 0; t < 16; ++t) {
            int idx = t * 256 + tid;
            int j = idx >> 5, lc = idx & 31;
            WT[lc * 132 + j] = W[j * 128 + l0 + lc];
        }
        __syncthreads();

        #pragma unroll 8
        for (int lc = 0; lc < 32; ++lc) {
            float4 wt = ((const float4*)(WT + lc * 132))[jc];
            #pragma unroll
            for (int ri = 0; ri < 4; ++ri) {
                float xv = xs[(rg * 4 + ri) * 128 + l0 + lc];
                acc[ri][0] += xv * wt.x;
                acc[ri][1] += xv * wt.y;
                acc[ri][2] += xv * wt.z;
                acc[ri][3] += xv * wt.w;
            }
        }
    }

    #pragma unroll
    for (int ri = 0; ri < 4; ++ri) {
        float ss = acc[ri][0]*acc[ri][0] + acc[ri][1]*acc[ri][1]
                 + acc[ri][2]*acc[ri][2] + acc[ri][3]*acc[ri][3];
        ss += __shfl_xor(ss, 1);
        ss += __shfl_xor(ss, 2);
        ss += __shfl_xor(ss, 4);
        float inv = 1.0f / fmaxf(sqrtf(ss), 1e-12f);
        int row = row0 + rg * 4 + ri;
        if (row < n) {
            float4 o;
            o.x = acc[ri][0]*inv; o.y = acc[ri][1]*inv;
            o.z = acc[ri][2]*inv; o.w = acc[ri][3]*inv;
            ((float4*)(h + (size_t)row * 128))[jc] = o;
        }
    }
}

// ---------------------------------------------------------------------------
// CSR build
// ---------------------------------------------------------------------------
__global__ void zero_kernel(int* __restrict__ p, int n)
{
    int i = blockIdx.x * blockDim.x + threadIdx.x;
    if (i < n) p[i] = 0;
}

__global__ void hist_kernel(const void* __restrict__ st, long long m, int n,
                            const int* __restrict__ idx64, int* __restrict__ cnt)
{
    long long e = (long long)blockIdx.x * blockDim.x + threadIdx.x;
    if (e < m) {
        int t = load_idx(st, m + e, *idx64);
        if (t >= 0 && t < n) atomicAdd(&cnt[t], 1);
    }
}

__global__ __launch_bounds__(1024)
void scan_kernel(const int* __restrict__ cnt, int n,
                 int* __restrict__ row_ptr, int* __restrict__ cursor)
{
    __shared__ int lds[1024];
    int t = threadIdx.x;
    int per = (n + 1023) / 1024;
    int lo = min(t * per, n), hi = min(lo + per, n);
    int s = 0;
    for (int i = lo; i < hi; ++i) s += cnt[i];
    lds[t] = s;
    __syncthreads();
    for (int off = 1; off < 1024; off <<= 1) {
        int v = (t >= off) ? lds[t - off] : 0;
        __syncthreads();
        lds[t] += v;
        __syncthreads();
    }
    int run = lds[t] - s;
    for (int i = lo; i < hi; ++i) {
        row_ptr[i] = run; cursor[i] = run; run += cnt[i];
    }
    if (t == 0) row_ptr[n] = lds[1023];
}

__global__ void scatter_kernel(const void* __restrict__ st, long long m, int n,
                               const int* __restrict__ idx64,
                               int* __restrict__ cursor, int* __restrict__ edge_src)
{
    long long e = (long long)blockIdx.x * blockDim.x + threadIdx.x;
    if (e < m) {
        int is64 = *idx64;
        int t = load_idx(st, m + e, is64);
        int s = load_idx(st, e, is64);
        if (t >= 0 && t < n) {
            int pos = atomicAdd(&cursor[t], 1);
            edge_src[pos] = s;
        }
    }
}

// ---------------------------------------------------------------------------
// Routing: one wave per node, 6 iterations fused, c in registers (fp32).
// Round-4 proven structure; ONLY change: the 4-step intra-row dot reduce is
// DPP (VALU) instead of shfl_xor (DS). Denominator sums (xor 16/32) and the
// norm remain proven shfl_xor. No LDS cache, no permlane asm.
// ---------------------------------------------------------------------------
__global__ __launch_bounds__(256)
void route_kernel(const float* __restrict__ h, const int* __restrict__ row_ptr,
                  const int* __restrict__ edge_src, float* __restrict__ out, int n)
{
    int wid  = (int)((blockIdx.x * 256u + threadIdx.x) >> 6);
    wid = __builtin_amdgcn_readfirstlane(wid);   // wave-uniform, make it scalar
    int lane = threadIdx.x & 63;
    if (wid >= n) return;

    const float2* __restrict__ h2 = (const float2*)h;
    float2 c = h2[(size_t)wid * 64 + lane];
    const int e0 = row_ptr[wid], e1 = row_ptr[wid + 1];

    #pragma unroll 1
    for (int it = 0; it < ROUTIT; ++it) {
        float a0 = c.x, a1 = c.y;
        int e = e0;
        for (; e + 1 < e1; e += 2) {
            int sa = edge_src[e];
            int sb = edge_src[e + 1];
            float2 za = h2[(size_t)sa * 64 + lane];
            float2 zb = h2[(size_t)sb * 64 + lane];
            float pa = za.x * c.x + za.y * c.y;
            float pb = zb.x * c.x + zb.y * c.y;
            pa = rowsum16(pa);                       // DPP, VALU pipe
            pb = rowsum16(pb);
            float ea = __expf(pa), eb = __expf(pb);  // |p|<=1, no overflow
            float da = ea + __shfl_xor(ea, 16);
            float db = eb + __shfl_xor(eb, 16);
            da += __shfl_xor(da, 32);
            db += __shfl_xor(db, 32);
            float wa = ea * __builtin_amdgcn_rcpf(da);
            float wb = eb * __builtin_amdgcn_rcpf(db);
            a0 += wa * za.x;  a1 += wa * za.y;
            a0 += wb * zb.x;  a1 += wb * zb.y;
        }
        if (e < e1) {
            int s = edge_src[e];
            float2 z = h2[(size_t)s * 64 + lane];
            float p = z.x * c.x + z.y * c.y;
            p = rowsum16(p);
            float ex = __expf(p);
            float d = ex + __shfl_xor(ex, 16);
            d += __shfl_xor(d, 32);
            float w = ex * __builtin_amdgcn_rcpf(d);
            a0 += w * z.x;  a1 += w * z.y;
        }
        // per-channel l2norm (proven round-4 shfl chain)
        float ss = a0 * a0 + a1 * a1;
        ss += __shfl_xor(ss, 1);
        ss += __shfl_xor(ss, 2);
        ss += __shfl_xor(ss, 4);
        ss += __shfl_xor(ss, 8);
        float inv = __builtin_amdgcn_rcpf(fmaxf(sqrtf(ss), 1e-12f));
        c.x = a0 * inv;
        c.y = a1 * inv;
    }
    ((float2*)out)[(size_t)wid * 64 + lane] = c;
}

// ---------------------------------------------------------------------------
extern "C" void kernel_launch(void* const* d_in, const int* in_sizes, int n_in,
                              void* d_out, int out_size, void* d_ws, size_t ws_size,
                              hipStream_t stream)
{
    const float* x       = (const float*)d_in[0];
    const void*  src_trg = d_in[1];
    const float* W       = (const float*)d_in[2];
    const float* b       = (const float*)d_in[3];
    float*       out     = (float*)d_out;

    int n = in_sizes[0] / 128;
    long long m = in_sizes[1] / 2;

    // workspace layout (~59 MB)
    float* h        = (float*)d_ws;                    // n*128 floats (51.2 MB)
    int*   cnt      = (int*)(h + (size_t)n * 128);     // n
    int*   row_ptr  = cnt + n;                         // n+1
    int*   cursor   = row_ptr + (n + 1);               // n
    int*   edge_src = cursor + n;                      // m ints (6.4 MB)
    int*   idx64    = edge_src + m;                    // 1 flag

    hipLaunchKernelGGL(detect_idx64_kernel, dim3(1), dim3(1), 0, stream,
                       (const int*)src_trg, idx64);
    hipLaunchKernelGGL(gemm_norm_kernel, dim3((n + 31) / 32), dim3(256), 0, stream,
                       x, W, b, h, n);
    hipLaunchKernelGGL(zero_kernel, dim3((n + 255) / 256), dim3(256), 0, stream, cnt, n);
    hipLaunchKernelGGL(hist_kernel, dim3((int)((m + 255) / 256)), dim3(256), 0, stream,
                       src_trg, m, n, idx64, cnt);
    hipLaunchKernelGGL(scan_kernel, dim3(1), dim3(1024), 0, stream, cnt, n, row_ptr, cursor);
    hipLaunchKernelGGL(scatter_kernel, dim3((int)((m + 255) / 256)), dim3(256), 0, stream,
                       src_trg, m, n, idx64, cursor, edge_src);
    hipLaunchKernelGGL(route_kernel, dim3((n + 3) / 4), dim3(256), 0, stream,
                       h, row_ptr, edge_src, out, n);
}

// Round 9
// 1045.853 us; speedup vs baseline: 1.6326x; 1.0335x over previous
//
#include <hip/hip_runtime.h>
#include <math.h>

#define ROUTIT 6
#define CAP 16   // cached edges per wave: 4 waves * 16 * 64 * 8B = 32 KB/block -> 5 blocks/CU

// ---------------------------------------------------------------------------
// Index dtype detection (harness delivers int indices as int32; reference
// declares int64 — detect which encoding is present at runtime).
// ---------------------------------------------------------------------------
__global__ void detect_idx64_kernel(const int* __restrict__ raw, int* __restrict__ flag)
{
    int all_zero = 1;
    for (int i = 1; i < 64; i += 2)
        if (raw[i] != 0) { all_zero = 0; break; }
    *flag = all_zero;   // 1 => int64 encoding, 0 => int32
}

__device__ __forceinline__ int load_idx(const void* p, long long i, int is64)
{
    if (is64) return (int)((const long long*)p)[i];
    return ((const int*)p)[i];
}

// ---------------------------------------------------------------------------
// Intra-row (16-lane) sum via DPP (VALU pipe) — verified correct in round 8.
// Cross-row sums stay on proven __shfl_xor. NO permlane asm (round-6/7 bug).
// ---------------------------------------------------------------------------
template <int CTRL>
__device__ __forceinline__ float dpp_add(float x)
{
    int y = __builtin_amdgcn_update_dpp(0, __float_as_int(x), CTRL, 0xf, 0xf, true);
    return x + __int_as_float(y);
}

// sum over the 16-lane row (every lane of the row gets the total)
__device__ __forceinline__ float rowsum16(float p)
{
    p = dpp_add<0xB1>(p);   // quad_perm [1,0,3,2] : xor 1
    p = dpp_add<0x4E>(p);   // quad_perm [2,3,0,1] : xor 2
    p = dpp_add<0x124>(p);  // row_ror:4
    p = dpp_add<0x128>(p);  // row_ror:8
    return p;
}

// per-edge contribution (verified round-8 math)
__device__ __forceinline__ void edge_contrib(float zx, float zy, float cx, float cy,
                                             float& a0, float& a1)
{
    float p = zx * cx + zy * cy;
    p = rowsum16(p);                    // 32-elem channel dot, |p| <= 1
    float ex = __expf(p);               // no max-subtraction needed
    float d = ex + __shfl_xor(ex, 16);  // softmax denom over 4 channels
    d += __shfl_xor(d, 32);
    float w = ex * __builtin_amdgcn_rcpf(d);
    a0 += w * zx;
    a1 += w * zy;
}

// ---------------------------------------------------------------------------
// GEMM + per-channel L2 normalize (fp32 h).
// ---------------------------------------------------------------------------
__global__ __launch_bounds__(256)
void gemm_norm_kernel(const float* __restrict__ x, const float* __restrict__ W,
                      const float* __restrict__ b, float* __restrict__ h, int n)
{
    __shared__ float WT[32 * 132];    // WT[lc*132 + j] = W[j][l0+lc]
    __shared__ float xs[32 * 128];

    const int tid  = threadIdx.x;
    const int jc   = tid & 31;        // col group: cols jc*4 .. jc*4+3
    const int rg   = tid >> 5;        // row group: rows rg*4 .. rg*4+3
    const int row0 = blockIdx.x * 32;
    const int ntot = n * 128;

    for (int t = 0; t < 16; ++t) {
        int idx  = t * 256 + tid;
        int gidx = row0 * 128 + idx;
        xs[idx] = (gidx < ntot) ? x[gidx] : 0.0f;
    }

    float4 bb = ((const float4*)b)[jc];
    float acc[4][4];
    #pragma unroll
    for (int ri = 0; ri < 4; ++ri) {
        acc[ri][0] = bb.x; acc[ri][1] = bb.y; acc[ri][2] = bb.z; acc[ri][3] = bb.w;
    }

    for (int l0 = 0; l0 < 128; l0 += 32) {
        __syncthreads();
        for (int t = 0; t < 16; ++t) {
            int idx = t * 256 + tid;
            int j = idx >> 5, lc = idx & 31;
            WT[lc * 132 + j] = W[j * 128 + l0 + lc];
        }
        __syncthreads();

        #pragma unroll 8
        for (int lc = 0; lc < 32; ++lc) {
            float4 wt = ((const float4*)(WT + lc * 132))[jc];
            #pragma unroll
            for (int ri = 0; ri < 4; ++ri) {
                float xv = xs[(rg * 4 + ri) * 128 + l0 + lc];
                acc[ri][0] += xv * wt.x;
                acc[ri][1] += xv * wt.y;
                acc[ri][2] += xv * wt.z;
                acc[ri][3] += xv * wt.w;
            }
        }
    }

    #pragma unroll
    for (int ri = 0; ri < 4; ++ri) {
        float ss = acc[ri][0]*acc[ri][0] + acc[ri][1]*acc[ri][1]
                 + acc[ri][2]*acc[ri][2] + acc[ri][3]*acc[ri][3];
        ss += __shfl_xor(ss, 1);
        ss += __shfl_xor(ss, 2);
        ss += __shfl_xor(ss, 4);
        float inv = 1.0f / fmaxf(sqrtf(ss), 1e-12f);
        int row = row0 + rg * 4 + ri;
        if (row < n) {
            float4 o;
            o.x = acc[ri][0]*inv; o.y = acc[ri][1]*inv;
            o.z = acc[ri][2]*inv; o.w = acc[ri][3]*inv;
            ((float4*)(h + (size_t)row * 128))[jc] = o;
        }
    }
}

// ---------------------------------------------------------------------------
// CSR build
// ---------------------------------------------------------------------------
__global__ void zero_kernel(int* __restrict__ p, int n)
{
    int i = blockIdx.x * blockDim.x + threadIdx.x;
    if (i < n) p[i] = 0;
}

__global__ void hist_kernel(const void* __restrict__ st, long long m, int n,
                            const int* __restrict__ idx64, int* __restrict__ cnt)
{
    long long e = (long long)blockIdx.x * blockDim.x + threadIdx.x;
    if (e < m) {
        int t = load_idx(st, m + e, *idx64);
        if (t >= 0 && t < n) atomicAdd(&cnt[t], 1);
    }
}

__global__ __launch_bounds__(1024)
void scan_kernel(const int* __restrict__ cnt, int n,
                 int* __restrict__ row_ptr, int* __restrict__ cursor)
{
    __shared__ int lds[1024];
    int t = threadIdx.x;
    int per = (n + 1023) / 1024;
    int lo = min(t * per, n), hi = min(lo + per, n);
    int s = 0;
    for (int i = lo; i < hi; ++i) s += cnt[i];
    lds[t] = s;
    __syncthreads();
    for (int off = 1; off < 1024; off <<= 1) {
        int v = (t >= off) ? lds[t - off] : 0;
        __syncthreads();
        lds[t] += v;
        __syncthreads();
    }
    int run = lds[t] - s;
    for (int i = lo; i < hi; ++i) {
        row_ptr[i] = run; cursor[i] = run; run += cnt[i];
    }
    if (t == 0) row_ptr[n] = lds[1023];
}

__global__ void scatter_kernel(const void* __restrict__ st, long long m, int n,
                               const int* __restrict__ idx64,
                               int* __restrict__ cursor, int* __restrict__ edge_src)
{
    long long e = (long long)blockIdx.x * blockDim.x + threadIdx.x;
    if (e < m) {
        int is64 = *idx64;
        int t = load_idx(st, m + e, is64);
        int s = load_idx(st, e, is64);
        if (t >= 0 && t < n) {
            int pos = atomicAdd(&cursor[t], 1);
            edge_src[pos] = s;
        }
    }
}

// ---------------------------------------------------------------------------
// Routing: one wave per node, 6 iterations fused, c in registers (fp32).
// Single delta vs verified round 8: iter 0 caches the first CAP edges' z-rows
// in LDS (wave-private, no barrier needed); iters 1..5 replay from LDS,
// cutting ~5/6 of the 4.9 GB/launch L3+HBM gather traffic.
// ---------------------------------------------------------------------------
__global__ __launch_bounds__(256)
void route_kernel(const float* __restrict__ h, const int* __restrict__ row_ptr,
                  const int* __restrict__ edge_src, float* __restrict__ out, int n)
{
    __shared__ float2 zls[4][CAP][64];

    int wv   = threadIdx.x >> 6;
    int wid  = __builtin_amdgcn_readfirstlane(blockIdx.x * 4 + wv);
    int lane = threadIdx.x & 63;
    if (wid >= n) return;

    const float2* __restrict__ h2 = (const float2*)h;
    float2 c = h2[(size_t)wid * 64 + lane];
    float cx = c.x, cy = c.y;

    const int e0  = row_ptr[wid], e1 = row_ptr[wid + 1];
    const int deg = e1 - e0;
    const int nc  = deg < CAP ? deg : CAP;

    // ---- iteration 0: gather, cache in LDS, compute ----
    float a0 = cx, a1 = cy;
    {
        int j = 0;
        for (; j + 1 < nc; j += 2) {
            int sa = edge_src[e0 + j];
            int sb = edge_src[e0 + j + 1];
            float2 za = h2[(size_t)sa * 64 + lane];
            float2 zb = h2[(size_t)sb * 64 + lane];
            zls[wv][j][lane] = za;
            zls[wv][j + 1][lane] = zb;
            edge_contrib(za.x, za.y, cx, cy, a0, a1);
            edge_contrib(zb.x, zb.y, cx, cy, a0, a1);
        }
        if (j < nc) {
            int s = edge_src[e0 + j];
            float2 z = h2[(size_t)s * 64 + lane];
            zls[wv][j][lane] = z;
            edge_contrib(z.x, z.y, cx, cy, a0, a1);
        }
        for (int e = e0 + nc; e < e1; ++e) {
            int s = edge_src[e];
            float2 z = h2[(size_t)s * 64 + lane];
            edge_contrib(z.x, z.y, cx, cy, a0, a1);
        }
        float ss = a0 * a0 + a1 * a1;
        ss += __shfl_xor(ss, 1);
        ss += __shfl_xor(ss, 2);
        ss += __shfl_xor(ss, 4);
        ss += __shfl_xor(ss, 8);
        float inv = __builtin_amdgcn_rcpf(fmaxf(sqrtf(ss), 1e-12f));
        cx = a0 * inv; cy = a1 * inv;
    }

    // ---- iterations 1..5: replay from LDS (+ uncached tail from global) ----
    #pragma unroll 1
    for (int it = 1; it < ROUTIT; ++it) {
        a0 = cx; a1 = cy;
        int j = 0;
        for (; j + 1 < nc; j += 2) {
            float2 za = zls[wv][j][lane];
            float2 zb = zls[wv][j + 1][lane];
            edge_contrib(za.x, za.y, cx, cy, a0, a1);
            edge_contrib(zb.x, zb.y, cx, cy, a0, a1);
        }
        if (j < nc) {
            float2 z = zls[wv][j][lane];
            edge_contrib(z.x, z.y, cx, cy, a0, a1);
        }
        for (int e = e0 + nc; e < e1; ++e) {
            int s = edge_src[e];
            float2 z = h2[(size_t)s * 64 + lane];
            edge_contrib(z.x, z.y, cx, cy, a0, a1);
        }
        float ss = a0 * a0 + a1 * a1;
        ss += __shfl_xor(ss, 1);
        ss += __shfl_xor(ss, 2);
        ss += __shfl_xor(ss, 4);
        ss += __shfl_xor(ss, 8);
        float inv = __builtin_amdgcn_rcpf(fmaxf(sqrtf(ss), 1e-12f));
        cx = a0 * inv; cy = a1 * inv;
    }

    float2 o; o.x = cx; o.y = cy;
    ((float2*)out)[(size_t)wid * 64 + lane] = o;
}

// ---------------------------------------------------------------------------
extern "C" void kernel_launch(void* const* d_in, const int* in_sizes, int n_in,
                              void* d_out, int out_size, void* d_ws, size_t ws_size,
                              hipStream_t stream)
{
    const float* x       = (const float*)d_in[0];
    const void*  src_trg = d_in[1];
    const float* W       = (const float*)d_in[2];
    const float* b       = (const float*)d_in[3];
    float*       out     = (float*)d_out;

    int n = in_sizes[0] / 128;
    long long m = in_sizes[1] / 2;

    // workspace layout (~59 MB)
    float* h        = (float*)d_ws;                    // n*128 floats (51.2 MB)
    int*   cnt      = (int*)(h + (size_t)n * 128);     // n
    int*   row_ptr  = cnt + n;                         // n+1
    int*   cursor   = row_ptr + (n + 1);               // n
    int*   edge_src = cursor + n;                      // m ints (6.4 MB)
    int*   idx64    = edge_src + m;                    // 1 flag

    hipLaunchKernelGGL(detect_idx64_kernel, dim3(1), dim3(1), 0, stream,
                       (const int*)src_trg, idx64);
    hipLaunchKernelGGL(gemm_norm_kernel, dim3((n + 31) / 32), dim3(256), 0, stream,
                       x, W, b, h, n);
    hipLaunchKernelGGL(zero_kernel, dim3((n + 255) / 256), dim3(256), 0, stream, cnt, n);
    hipLaunchKernelGGL(hist_kernel, dim3((int)((m + 255) / 256)), dim3(256), 0, stream,
                       src_trg, m, n, idx64, cnt);
    hipLaunchKernelGGL(scan_kernel, dim3(1), dim3(1024), 0, stream, cnt, n, row_ptr, cursor);
    hipLaunchKernelGGL(scatter_kernel, dim3((int)((m + 255) / 256)), dim3(256), 0, stream,
                       src_trg, m, n, idx64, cursor, edge_src);
    hipLaunchKernelGGL(route_kernel, dim3((n + 3) / 4), dim3(256), 0, stream,
                       h, row_ptr, edge_src, out, n);
}